// Round 18
// baseline (82.883 us; speedup 1.0000x reference)
//
#include <hip/hip_runtime.h>
#include <stdint.h>

#define HW 4096
#define NC 256
#define NP 8
#define NB 32
#define CHW 32            // hw per chunk (32 KB tile)
#define NCHK 16           // chunks per block (512 hw span)
#define NOCT 8            // blocks per batch
#define NBLK (NB * NOCT)  // 256 blocks = 1 per CU

#define FMA4(acc, v, s)                  \
  acc.x = fmaf((v).x, (s), acc.x);       \
  acc.y = fmaf((v).y, (s), acc.y);       \
  acc.z = fmaf((v).z, (s), acc.z);       \
  acc.w = fmaf((v).w, (s), acc.w)

// async 16B/lane global->LDS: lds dest = wave-uniform base + lane*16 (HW rule)
__device__ __forceinline__ void gload_lds16(const float* g, float* l) {
  __builtin_amdgcn_global_load_lds(
      (const __attribute__((address_space(1))) uint32_t*)g,
      (__attribute__((address_space(3))) uint32_t*)l, 16, 0, 0);
}

// ---------------- Fused async-pipelined: per (b, 512-hw octant) block ----------------
// 512 threads (8 waves), 1 block/CU (LDS 145 KB). 4-deep ring of 32-KB chunks
// staged via global_load_lds (no VGPRs -> no spill; loads live ACROSS barriers).
// Raw s_barrier + counted vmcnt (never 0 mid-loop): chunk k awaited 3 iters
// after issue -> HBM continuously fed (fixes R4-R17 phase serialization).
// Swizzle via pre-swizzled GLOBAL source (linear LDS dest): lane l stages
// logical seg (l&7)^(l>>3) of row base+(l>>3); slot s of row r holds logical
// s^(r&7); readers XOR accordingly. All LDS patterns 8 lanes/bank-window.
// e = exp(score+bias); no max-subtract (|s|<~5; ratios identical; absmax
// ~1e-7 validated R1-R17).
__global__ __launch_bounds__(512) void k_fused(
    const float* __restrict__ x, const float* __restrict__ Wm,
    const float* __restrict__ bias, float* __restrict__ partial,
    float* __restrict__ psum) {
  __shared__ __align__(16) float xs[4][NC][CHW];   // 128 KB ring
  __shared__ __align__(16) float wt[NC][NP];       // 8 KB W^T
  __shared__ __align__(16) float sp[8][NP][CHW];   // 8 KB score partials
  __shared__ __align__(16) float els[NP][CHW];     // 1 KB e values

  const int bid = blockIdx.x;
  const int b = bid >> 3;
  const int oct = bid & 7;
  const int t = threadIdx.x, lane = t & 63, w = t >> 6;  // 8 waves
  const float* xb = x + (size_t)b * NC * HW + oct * (NCHK * CHW);

  // ---- stage W^T (once; ds_writes complete before first top-barrier) ----
#pragma unroll
  for (int i = 0; i < 4; ++i) {
    int idx = i * 512 + t;              // p*256 + c
    wt[idx & 255][idx >> 8] = Wm[idx];
  }

  // ---- per-lane staging geometry ----
  const int cr = lane >> 3;                       // row-in-group 0..7
  const int q = lane & 7;                         // slot 0..7
  const int rbase = (w << 5) + cr;                // wave's row + lane row
  const int sseg = (q ^ cr) << 2;                 // pre-swizzled logical seg (floats)
  const float* gbase = xb + (size_t)rbase * HW + sseg;

  const int ep = (t & 255) >> 5, eh = t & 31;     // e-phase mapping (t<256 active)
  const float bia = bias[ep];
  const int brow = t >> 1, bh = (t & 1) * 4;      // B-phase: row + seg-half
  const int bx7 = brow & 7;

  float pacc[NP];
#pragma unroll
  for (int p = 0; p < NP; ++p) pacc[p] = 0.f;
  float esum_tot = 0.f;

  // ---- prologue: issue chunks 0..2 (4 instrs/wave each; 12 outstanding) ----
#pragma unroll
  for (int k0 = 0; k0 < 3; ++k0) {
#pragma unroll
    for (int i = 0; i < 4; ++i)
      gload_lds16(gbase + (size_t)(i * 8) * HW + k0 * CHW,
                  &xs[k0][(w << 5) + (i << 3)][0]);
  }

#pragma unroll 1
  for (int k = 0; k < NCHK; ++k) {
    // ---- top: chunk k landed (mine: oldest 4 of <=12); prior ds ops done; sync ----
    if (k <= 13)      asm volatile("s_waitcnt vmcnt(8) lgkmcnt(0)" ::: "memory");
    else if (k == 14) asm volatile("s_waitcnt vmcnt(4) lgkmcnt(0)" ::: "memory");
    else              asm volatile("s_waitcnt vmcnt(0) lgkmcnt(0)" ::: "memory");
    __builtin_amdgcn_s_barrier();
    __builtin_amdgcn_sched_barrier(0);

    // ---- issue chunk k+3 into ring slot (k+3)&3 (read finished at iter k-1) ----
    if (k + 3 < NCHK) {
      const float* g = gbase + (size_t)((k + 3) * CHW);
#pragma unroll
      for (int i = 0; i < 4; ++i)
        gload_lds16(g + (size_t)(i * 8) * HW,
                    &xs[(k + 3) & 3][(w << 5) + (i << 3)][0]);
    }

    const int buf = k & 3;

    // ---- Phase A: wave w -> rows 32w..32w+31; lane reads its own staged segs ----
    {
      float4 s4[NP];
#pragma unroll
      for (int p = 0; p < NP; ++p) s4[p] = make_float4(0.f, 0.f, 0.f, 0.f);
#pragma unroll
      for (int i = 0; i < 4; ++i) {
        const int c = (w << 5) + (i << 3) + cr;
        const float4 xv = *(const float4*)&xs[buf][c][sseg];   // slot (q^cr)
        const float4 wA = *(const float4*)&wt[c][0];           // 2-way alias: free
        const float4 wB = *(const float4*)&wt[c][4];
        FMA4(s4[0], xv, wA.x);
        FMA4(s4[1], xv, wA.y);
        FMA4(s4[2], xv, wA.z);
        FMA4(s4[3], xv, wA.w);
        FMA4(s4[4], xv, wB.x);
        FMA4(s4[5], xv, wB.y);
        FMA4(s4[6], xv, wB.z);
        FMA4(s4[7], xv, wB.w);
      }
      // cr-reduce once (lane bits 3,4,5); cr==0 lanes write sp[w]
#pragma unroll
      for (int p = 0; p < NP; ++p) {
        float4 v = s4[p];
        v.x += __shfl_xor(v.x, 8);  v.y += __shfl_xor(v.y, 8);
        v.z += __shfl_xor(v.z, 8);  v.w += __shfl_xor(v.w, 8);
        v.x += __shfl_xor(v.x, 16); v.y += __shfl_xor(v.y, 16);
        v.z += __shfl_xor(v.z, 16); v.w += __shfl_xor(v.w, 16);
        v.x += __shfl_xor(v.x, 32); v.y += __shfl_xor(v.y, 32);
        v.z += __shfl_xor(v.z, 32); v.w += __shfl_xor(v.w, 32);
        if (cr == 0) *(float4*)&sp[w][p][q * 4] = v;  // 8 lanes x 16B: all banks
      }
    }
    asm volatile("s_waitcnt lgkmcnt(0)" ::: "memory");  // sp writes done
    __builtin_amdgcn_s_barrier();

    // ---- e-phase (t<256): exp(bias + sum over 8 waves) ----
    if (t < 256) {
      float a = bia;
#pragma unroll
      for (int ww = 0; ww < 8; ++ww) a += sp[ww][ep][eh];
      const float e0 = expf(a);
      els[ep][eh] = e0;
      esum_tot += e0;
    }
    asm volatile("s_waitcnt lgkmcnt(0)" ::: "memory");  // els writes done
    __builtin_amdgcn_s_barrier();

    // ---- Phase B: thread = half-row (row t>>1, segs bh..bh+3) ----
#pragma unroll
    for (int j = 0; j < 4; ++j) {
      const int seg = bh + j;
      const float4 xv = *(const float4*)&xs[buf][brow][(seg ^ bx7) << 2];
#pragma unroll
      for (int p = 0; p < NP; ++p) {
        const float4 e4 = *(const float4*)&els[p][seg << 2];  // 2-addr bcast
        pacc[p] = fmaf(xv.x, e4.x, pacc[p]);
        pacc[p] = fmaf(xv.y, e4.y, pacc[p]);
        pacc[p] = fmaf(xv.z, e4.z, pacc[p]);
        pacc[p] = fmaf(xv.w, e4.w, pacc[p]);
      }
    }
    // B's ds_reads drained by next iteration's top lgkmcnt(0)+barrier
  }

  // ---- epilogue: combine row halves; even threads write partial[bid][p][row] ----
#pragma unroll
  for (int p = 0; p < NP; ++p) {
    float v = pacc[p] + __shfl_xor(pacc[p], 1);
    if ((t & 1) == 0)
      partial[((size_t)bid * NP + p) * NC + brow] = v;
  }

  // ---- psum[bid][ep]: esum reduced over the 32 eh-lanes (t<256) ----
#pragma unroll
  for (int off = 16; off; off >>= 1) esum_tot += __shfl_xor(esum_tot, off);
  if (t < 256 && eh == 0) psum[bid * NP + ep] = esum_tot;
}

// ---------------- Reduce: out[b,p,c] = ginv * sum_oct partial ----------------
__global__ __launch_bounds__(256) void k_reduce(
    const float* __restrict__ partial, const float* __restrict__ psum,
    float* __restrict__ out) {
  int bp = blockIdx.x;  // b*8 + p
  int b = bp >> 3, p = bp & 7;
  int t = threadIdx.x, lane = t & 63, w2 = t >> 6;

  __shared__ float gv;
  if (w2 == 0) {
    float v = (lane < NOCT) ? psum[(size_t)(b * NOCT + lane) * NP + p] : 0.f;
#pragma unroll
    for (int off = 4; off; off >>= 1) v += __shfl_xor(v, off);
    if (lane == 0) gv = 1.0f / (v * (float)HW);
  }
  __syncthreads();
  float ginv = gv;

  float acc = 0.f;
#pragma unroll
  for (int i = 0; i < NOCT; ++i)
    acc += partial[(((size_t)b * NOCT + i) * NP + p) * NC + t];
  out[((size_t)b * NP + p) * NC + t] = acc * ginv;
}

extern "C" void kernel_launch(void* const* d_in, const int* in_sizes, int n_in,
                              void* d_out, int out_size, void* d_ws, size_t ws_size,
                              hipStream_t stream) {
  const float* x = (const float*)d_in[0];
  const float* Wm = (const float*)d_in[1];
  const float* bias = (const float*)d_in[2];
  float* out = (float*)d_out;

  float* ws = (float*)d_ws;
  float* partial = ws;                              // 256*8*256 floats = 2 MiB
  float* psum = ws + (size_t)NBLK * NP * NC;        // 256*8 floats

  k_fused<<<NBLK, 512, 0, stream>>>(x, Wm, bias, partial, psum);
  k_reduce<<<NB * NP, 256, 0, stream>>>(partial, psum, out);
}